// Round 2
// baseline (538.465 us; speedup 1.0000x reference)
//
#include <hip/hip_runtime.h>

#define MFULL 16384
#define MOUT  2048
#define H     4096
#define WS    8
#define KSPLIT 2
#define KHALF (H / KSPLIT)

typedef _Float16 f16x8 __attribute__((ext_vector_type(8)));
typedef _Float16 f16x4 __attribute__((ext_vector_type(4)));
typedef _Float16 f16x2 __attribute__((ext_vector_type(2)));
typedef float    f32x4 __attribute__((ext_vector_type(4)));
typedef float    f32x2 __attribute__((ext_vector_type(2)));

// fp8(e4m3 OCP, RNE) round-trip of 4 floats via HW cvt instructions
__device__ __forceinline__ void fp8_rt4(float4& v) {
    int p0 = __builtin_amdgcn_cvt_pk_fp8_f32(v.x, v.y, 0, false);
    int p1 = __builtin_amdgcn_cvt_pk_fp8_f32(v.z, v.w, 0, false);
    f32x2 r0 = __builtin_amdgcn_cvt_pk_f32_fp8(p0, false);
    f32x2 r1 = __builtin_amdgcn_cvt_pk_f32_fp8(p1, false);
    v.x = r0.x; v.y = r0.y; v.z = r1.x; v.w = r1.y;
}

__device__ __forceinline__ float fp8_rt1(float x) {
    int p = __builtin_amdgcn_cvt_pk_fp8_f32(x, x, 0, false);
    return __builtin_amdgcn_cvt_f32_fp8(p, 0);
}

__device__ __forceinline__ void async_copy16(const void* g, void* l) {
    __builtin_amdgcn_global_load_lds(
        (const __attribute__((address_space(1))) void*)g,
        (__attribute__((address_space(3))) void*)l, 16, 0, 0);
}

// Pass 1a: A'[r,k] = sum_{s=0..7} fp8(input[s*2048+r, k]), stored fp16.
__global__ void reduce_quant_a(const float* __restrict__ in,
                               _Float16* __restrict__ aq) {
    int idx = blockIdx.x * 256 + threadIdx.x;       // [0, 2048*1024)
    int r = idx >> 10;                               // row 0..2047
    int k = (idx & 1023) * 4;
    const float* p = in + (size_t)r * H + k;
    float4 acc = {0.f, 0.f, 0.f, 0.f};
#pragma unroll
    for (int s = 0; s < WS; ++s) {
        float4 v = *(const float4*)(p + (size_t)s * MOUT * H);
        fp8_rt4(v);
        acc.x += v.x; acc.y += v.y; acc.z += v.z; acc.w += v.w;
    }
    f16x4 h = { (_Float16)acc.x, (_Float16)acc.y, (_Float16)acc.z, (_Float16)acc.w };
    *(f16x4*)(aq + (size_t)r * H + k) = h;
}

// Pass 1b: B^T[n,k] = fp16(fp8(weight[k,n])). 64x64 tile transpose via LDS.
__global__ void quant_transpose_b(const float* __restrict__ w,
                                  _Float16* __restrict__ bt) {
    __shared__ _Float16 tile[64][66];
    int t  = threadIdx.x;
    int n0 = blockIdx.x * 64;
    int k0 = blockIdx.y * 64;
#pragma unroll
    for (int i = 0; i < 16; ++i) {
        int lin = i * 256 + t;
        int kl = lin >> 6;
        int nl = lin & 63;
        float v = w[(size_t)(k0 + kl) * H + n0 + nl];
        tile[kl][nl] = (_Float16)fp8_rt1(v);
    }
    __syncthreads();
#pragma unroll
    for (int i = 0; i < 8; ++i) {
        int lin = i * 256 + t;
        int kl = (lin & 31) * 2;
        int nl = lin >> 5;
        f16x2 hv = { tile[kl][nl], tile[kl + 1][nl] };
        *(f16x2*)(bt + (size_t)(n0 + nl) * H + k0 + kl) = hv;
    }
}

// Pass 2: split-K GEMM. P[z][2048,4096] = A'[:, z*2048:(z+1)*2048] @ B'[z-half]
// 128x128 block tile, BK=32, 4 waves (2x2 of 64x64), mfma_f32_16x16x32_f16.
// grid (32, 16, 2) = 1024 blocks -> ~3 resident blocks/CU (vs 2 at 512).
__global__ __launch_bounds__(256) void gemm_splitk(
    const _Float16* __restrict__ A, const _Float16* __restrict__ Bt,
    float* __restrict__ P) {
    __shared__ _Float16 As[128 * 32];
    __shared__ _Float16 Bs[128 * 32];

    const int tid  = threadIdx.x;
    const int wid  = tid >> 6;
    const int lane = tid & 63;
    const int quad = lane >> 4;
    const int l16  = lane & 15;
    const int bm   = blockIdx.y * 128;
    const int bn   = blockIdx.x * 128;
    const int koff = blockIdx.z * KHALF;
    const int wm   = (wid >> 1) * 64;
    const int wn   = (wid & 1) * 64;

    f32x4 acc[4][4] = {};

    const _Float16* Ab = A  + (size_t)bm * H + koff;
    const _Float16* Bb = Bt + (size_t)bn * H + koff;

    // staging: chunk = (t*4+wid)*64 + lane; row = chunk>>2, slot = chunk&3,
    // kc = slot ^ ((row>>2)&3)  (XOR swizzle breaks 8-way ds_read conflict)
    int chunk0 = wid * 64 + lane;
    int row0 = chunk0 >> 2, s0 = chunk0 & 3;
    int kc0 = s0 ^ ((row0 >> 2) & 3);
    int chunk1 = (4 + wid) * 64 + lane;
    int row1 = chunk1 >> 2, s1 = chunk1 & 3;
    int kc1 = s1 ^ ((row1 >> 2) & 3);

    const size_t ga0 = (size_t)row0 * H + kc0 * 8;
    const size_t ga1 = (size_t)row1 * H + kc1 * 8;
    char* la0 = (char*)As + wid * 1024;
    char* la1 = (char*)As + (4 + wid) * 1024;
    char* lb0 = (char*)Bs + wid * 1024;
    char* lb1 = (char*)Bs + (4 + wid) * 1024;

    const int fslot = quad ^ (l16 >> 2);
    const int foff  = fslot * 8;   // halfs

    for (int k0 = 0; k0 < KHALF; k0 += 32) {
        async_copy16(Ab + ga0 + k0, la0);
        async_copy16(Ab + ga1 + k0, la1);
        async_copy16(Bb + ga0 + k0, lb0);
        async_copy16(Bb + ga1 + k0, lb1);
        __syncthreads();

        f16x8 af[4], bf[4];
#pragma unroll
        for (int i = 0; i < 4; ++i)
            af[i] = *(const f16x8*)&As[(wm + i * 16 + l16) * 32 + foff];
#pragma unroll
        for (int i = 0; i < 4; ++i)
            bf[i] = *(const f16x8*)&Bs[(wn + i * 16 + l16) * 32 + foff];
#pragma unroll
        for (int i = 0; i < 4; ++i)
#pragma unroll
            for (int j = 0; j < 4; ++j)
                acc[i][j] = __builtin_amdgcn_mfma_f32_16x16x32_f16(
                    af[i], bf[j], acc[i][j], 0, 0, 0);
        __syncthreads();
    }

    float* Pz = P + (size_t)blockIdx.z * MOUT * H;
#pragma unroll
    for (int i = 0; i < 4; ++i) {
#pragma unroll
        for (int j = 0; j < 4; ++j) {
            int col = bn + wn + j * 16 + l16;
#pragma unroll
            for (int r = 0; r < 4; ++r) {
                int row = bm + wm + i * 16 + quad * 4 + r;
                Pz[(size_t)row * H + col] = acc[i][j][r];
            }
        }
    }
}

// Pass 3: out = fp16((P0 + P1) * scale_b), stored as fp32 values.
__global__ void reduce_scale(const float* __restrict__ P,
                             const float* __restrict__ scale_b,
                             float* __restrict__ out) {
    int idx = blockIdx.x * 256 + threadIdx.x;        // [0, 2048*1024)
    int c4 = (idx & (H / 4 - 1)) * 4;
    float4 p0 = ((const float4*)P)[idx];
    float4 p1 = ((const float4*)(P + (size_t)MOUT * H))[idx];
    float4 sb = *(const float4*)(scale_b + c4);
    float4 r;
    r.x = (float)(_Float16)((p0.x + p1.x) * sb.x);
    r.y = (float)(_Float16)((p0.y + p1.y) * sb.y);
    r.z = (float)(_Float16)((p0.z + p1.z) * sb.z);
    r.w = (float)(_Float16)((p0.w + p1.w) * sb.w);
    ((float4*)out)[idx] = r;
}

extern "C" void kernel_launch(void* const* d_in, const int* in_sizes, int n_in,
                              void* d_out, int out_size, void* d_ws, size_t ws_size,
                              hipStream_t stream) {
    const float* input   = (const float*)d_in[0];   // [16384, 4096] fp32
    const float* weight  = (const float*)d_in[1];   // [4096, 4096] fp32
    const float* scale_b = (const float*)d_in[2];   // [1, 4096] fp32
    float* out = (float*)d_out;                     // [2048, 4096] (fp16 values)

    _Float16* aq = (_Float16*)d_ws;                          // 16 MB
    _Float16* bt = aq + (size_t)MOUT * H;                    // 32 MB
    float*    P  = (float*)(bt + (size_t)H * H);             // 64 MB partials

    reduce_quant_a<<<(MOUT * H / 4) / 256, 256, 0, stream>>>(input, aq);
    quant_transpose_b<<<dim3(H / 64, H / 64), 256, 0, stream>>>(weight, bt);
    gemm_splitk<<<dim3(H / 128, MOUT / 128, KSPLIT), 256, 0, stream>>>(aq, bt, P);
    reduce_scale<<<(MOUT * H / 4) / 256, 256, 0, stream>>>(P, scale_b, out);
}

// Round 3
// 511.135 us; speedup vs baseline: 1.0535x; 1.0535x over previous
//
#include <hip/hip_runtime.h>

#define MFULL 16384
#define MOUT  2048
#define H     4096
#define WS    8

typedef _Float16 f16x8 __attribute__((ext_vector_type(8)));
typedef _Float16 f16x4 __attribute__((ext_vector_type(4)));
typedef _Float16 f16x2 __attribute__((ext_vector_type(2)));
typedef float    f32x4 __attribute__((ext_vector_type(4)));
typedef float    f32x2 __attribute__((ext_vector_type(2)));

// fp8(e4m3 OCP, RNE) round-trip via HW cvt instructions
__device__ __forceinline__ void fp8_rt4(float4& v) {
    int p0 = __builtin_amdgcn_cvt_pk_fp8_f32(v.x, v.y, 0, false);
    int p1 = __builtin_amdgcn_cvt_pk_fp8_f32(v.z, v.w, 0, false);
    f32x2 r0 = __builtin_amdgcn_cvt_pk_f32_fp8(p0, false);
    f32x2 r1 = __builtin_amdgcn_cvt_pk_f32_fp8(p1, false);
    v.x = r0.x; v.y = r0.y; v.z = r1.x; v.w = r1.y;
}

__device__ __forceinline__ void async_copy16(const void* g, void* l) {
    __builtin_amdgcn_global_load_lds(
        (const __attribute__((address_space(1))) void*)g,
        (__attribute__((address_space(3))) void*)l, 16, 0, 0);
}

// Pass 1a: A'[r,k] = sum_{s=0..7} fp8(input[s*2048+r, k]), stored fp16.
// Memory-bound floor: 256 MB read + 16 MB write ≈ 43 µs.
__global__ void reduce_quant_a(const float* __restrict__ in,
                               _Float16* __restrict__ aq) {
    int idx = blockIdx.x * 256 + threadIdx.x;       // [0, 2048*1024)
    int r = idx >> 10;                               // row 0..2047
    int k = (idx & 1023) * 4;
    const float* p = in + (size_t)r * H + k;
    float4 acc = {0.f, 0.f, 0.f, 0.f};
#pragma unroll
    for (int s = 0; s < WS; ++s) {
        float4 v = *(const float4*)(p + (size_t)s * MOUT * H);
        fp8_rt4(v);
        acc.x += v.x; acc.y += v.y; acc.z += v.z; acc.w += v.w;
    }
    f16x4 h = { (_Float16)acc.x, (_Float16)acc.y, (_Float16)acc.z, (_Float16)acc.w };
    *(f16x4*)(aq + (size_t)r * H + k) = h;
}

// Pass 1b: B^T[n,k] = fp16(fp8(weight[k,n])). 64x64 tile transpose via LDS,
// float4 global loads (4 consecutive n per thread).
__global__ void quant_transpose_b(const float* __restrict__ w,
                                  _Float16* __restrict__ bt) {
    __shared__ _Float16 tile[64][66];
    int t  = threadIdx.x;
    int n0 = blockIdx.x * 64;
    int k0 = blockIdx.y * 64;
    // load: 64x64 fp32 tile, 16 float4 per row, 256 threads -> 4 iters
#pragma unroll
    for (int i = 0; i < 4; ++i) {
        int lin = i * 256 + t;          // [0,1024)
        int kl = lin >> 4;              // row 0..63
        int nl = (lin & 15) * 4;        // col 0,4,..,60
        float4 v = *(const float4*)(w + (size_t)(k0 + kl) * H + n0 + nl);
        fp8_rt4(v);
        tile[kl][nl + 0] = (_Float16)v.x;
        tile[kl][nl + 1] = (_Float16)v.y;
        tile[kl][nl + 2] = (_Float16)v.z;
        tile[kl][nl + 3] = (_Float16)v.w;
    }
    __syncthreads();
#pragma unroll
    for (int i = 0; i < 8; ++i) {
        int lin = i * 256 + t;
        int kl = (lin & 31) * 2;
        int nl = lin >> 5;
        f16x2 hv = { tile[kl][nl], tile[kl + 1][nl] };
        *(f16x2*)(bt + (size_t)(n0 + nl) * H + k0 + kl) = hv;
    }
}

// Pass 2: C[2048,4096] = A' @ B'  (B' as B^T [N][K]), scale_b fused epilogue.
// 128x128 tile, BK=32, 4 waves (2x2 of 64x64), mfma_f32_16x16x32_f16,
// global_load_lds width=16, XOR swizzle kc = slot ^ ((row>>2)&3).
__global__ __launch_bounds__(256) void gemm_rs(
    const _Float16* __restrict__ A, const _Float16* __restrict__ Bt,
    const float* __restrict__ scale_b, float* __restrict__ out) {
    __shared__ _Float16 As[128 * 32];
    __shared__ _Float16 Bs[128 * 32];

    const int tid  = threadIdx.x;
    const int wid  = tid >> 6;
    const int lane = tid & 63;
    const int quad = lane >> 4;
    const int l16  = lane & 15;
    const int bm   = blockIdx.y * 128;
    const int bn   = blockIdx.x * 128;
    const int wm   = (wid >> 1) * 64;
    const int wn   = (wid & 1) * 64;

    f32x4 acc[4][4] = {};

    const _Float16* Ab = A  + (size_t)bm * H;
    const _Float16* Bb = Bt + (size_t)bn * H;

    int chunk0 = wid * 64 + lane;
    int row0 = chunk0 >> 2, s0 = chunk0 & 3;
    int kc0 = s0 ^ ((row0 >> 2) & 3);
    int chunk1 = (4 + wid) * 64 + lane;
    int row1 = chunk1 >> 2, s1 = chunk1 & 3;
    int kc1 = s1 ^ ((row1 >> 2) & 3);

    const size_t ga0 = (size_t)row0 * H + kc0 * 8;
    const size_t ga1 = (size_t)row1 * H + kc1 * 8;
    char* la0 = (char*)As + wid * 1024;
    char* la1 = (char*)As + (4 + wid) * 1024;
    char* lb0 = (char*)Bs + wid * 1024;
    char* lb1 = (char*)Bs + (4 + wid) * 1024;

    const int fslot = quad ^ (l16 >> 2);
    const int foff  = fslot * 8;   // halfs

    for (int k0 = 0; k0 < H; k0 += 32) {
        async_copy16(Ab + ga0 + k0, la0);
        async_copy16(Ab + ga1 + k0, la1);
        async_copy16(Bb + ga0 + k0, lb0);
        async_copy16(Bb + ga1 + k0, lb1);
        __syncthreads();

        f16x8 af[4], bf[4];
#pragma unroll
        for (int i = 0; i < 4; ++i)
            af[i] = *(const f16x8*)&As[(wm + i * 16 + l16) * 32 + foff];
#pragma unroll
        for (int i = 0; i < 4; ++i)
            bf[i] = *(const f16x8*)&Bs[(wn + i * 16 + l16) * 32 + foff];
#pragma unroll
        for (int i = 0; i < 4; ++i)
#pragma unroll
            for (int j = 0; j < 4; ++j)
                acc[i][j] = __builtin_amdgcn_mfma_f32_16x16x32_f16(
                    af[i], bf[j], acc[i][j], 0, 0, 0);
        __syncthreads();
    }

    // Epilogue: D[row=(lane>>4)*4+r][col=lane&15] per 16x16 tile, fp16-round
#pragma unroll
    for (int i = 0; i < 4; ++i) {
#pragma unroll
        for (int j = 0; j < 4; ++j) {
            int col = bn + wn + j * 16 + l16;
            float sb = scale_b[col];
#pragma unroll
            for (int r = 0; r < 4; ++r) {
                int row = bm + wm + i * 16 + quad * 4 + r;
                float v = acc[i][j][r] * sb;
                out[(size_t)row * H + col] = (float)(_Float16)v;
            }
        }
    }
}

extern "C" void kernel_launch(void* const* d_in, const int* in_sizes, int n_in,
                              void* d_out, int out_size, void* d_ws, size_t ws_size,
                              hipStream_t stream) {
    const float* input   = (const float*)d_in[0];   // [16384, 4096] fp32
    const float* weight  = (const float*)d_in[1];   // [4096, 4096] fp32
    const float* scale_b = (const float*)d_in[2];   // [1, 4096] fp32
    float* out = (float*)d_out;                     // [2048, 4096] (fp16 values)

    _Float16* aq = (_Float16*)d_ws;                 // 16 MB
    _Float16* bt = aq + (size_t)MOUT * H;           // 32 MB

    reduce_quant_a<<<(MOUT * H / 4) / 256, 256, 0, stream>>>(input, aq);
    quant_transpose_b<<<dim3(H / 64, H / 64), 256, 0, stream>>>(weight, bt);
    gemm_rs<<<dim3(H / 128, MOUT / 128), 256, 0, stream>>>(aq, bt, scale_b, out);
}

// Round 4
// 506.952 us; speedup vs baseline: 1.0622x; 1.0083x over previous
//
#include <hip/hip_runtime.h>

#define MFULL 16384
#define MOUT  2048
#define H     4096
#define WS    8
#define BK    64

typedef _Float16 f16x8 __attribute__((ext_vector_type(8)));
typedef _Float16 f16x4 __attribute__((ext_vector_type(4)));
typedef _Float16 f16x2 __attribute__((ext_vector_type(2)));
typedef float    f32x4 __attribute__((ext_vector_type(4)));
typedef float    f32x2 __attribute__((ext_vector_type(2)));

// fp8(e4m3 OCP, RNE) round-trip via HW cvt instructions
__device__ __forceinline__ void fp8_rt4(float4& v) {
    int p0 = __builtin_amdgcn_cvt_pk_fp8_f32(v.x, v.y, 0, false);
    int p1 = __builtin_amdgcn_cvt_pk_fp8_f32(v.z, v.w, 0, false);
    f32x2 r0 = __builtin_amdgcn_cvt_pk_f32_fp8(p0, false);
    f32x2 r1 = __builtin_amdgcn_cvt_pk_f32_fp8(p1, false);
    v.x = r0.x; v.y = r0.y; v.z = r1.x; v.w = r1.y;
}

__device__ __forceinline__ void async_copy16(const void* g, void* l) {
    __builtin_amdgcn_global_load_lds(
        (const __attribute__((address_space(1))) void*)g,
        (__attribute__((address_space(3))) void*)l, 16, 0, 0);
}

// Pass 1a: A'[r,k] = sum_{s=0..7} fp8(input[s*2048+r, k]), stored fp16.
__global__ void reduce_quant_a(const float* __restrict__ in,
                               _Float16* __restrict__ aq) {
    int idx = blockIdx.x * 256 + threadIdx.x;       // [0, 2048*1024)
    int r = idx >> 10;                               // row 0..2047
    int k = (idx & 1023) * 4;
    const float* p = in + (size_t)r * H + k;
    float4 acc = {0.f, 0.f, 0.f, 0.f};
#pragma unroll
    for (int s = 0; s < WS; ++s) {
        float4 v = *(const float4*)(p + (size_t)s * MOUT * H);
        fp8_rt4(v);
        acc.x += v.x; acc.y += v.y; acc.z += v.z; acc.w += v.w;
    }
    f16x4 h = { (_Float16)acc.x, (_Float16)acc.y, (_Float16)acc.z, (_Float16)acc.w };
    *(f16x4*)(aq + (size_t)r * H + k) = h;
}

// Pass 1b: B^T[n,k] = fp16(fp8(weight[k,n])). 64x64 tile transpose via LDS.
__global__ void quant_transpose_b(const float* __restrict__ w,
                                  _Float16* __restrict__ bt) {
    __shared__ _Float16 tile[64][66];
    int t  = threadIdx.x;
    int n0 = blockIdx.x * 64;
    int k0 = blockIdx.y * 64;
#pragma unroll
    for (int i = 0; i < 4; ++i) {
        int lin = i * 256 + t;          // [0,1024)
        int kl = lin >> 4;              // row 0..63
        int nl = (lin & 15) * 4;        // col 0,4,..,60
        float4 v = *(const float4*)(w + (size_t)(k0 + kl) * H + n0 + nl);
        fp8_rt4(v);
        tile[kl][nl + 0] = (_Float16)v.x;
        tile[kl][nl + 1] = (_Float16)v.y;
        tile[kl][nl + 2] = (_Float16)v.z;
        tile[kl][nl + 3] = (_Float16)v.w;
    }
    __syncthreads();
#pragma unroll
    for (int i = 0; i < 8; ++i) {
        int lin = i * 256 + t;
        int kl = (lin & 31) * 2;
        int nl = lin >> 5;
        f16x2 hv = { tile[kl][nl], tile[kl + 1][nl] };
        *(f16x2*)(bt + (size_t)(n0 + nl) * H + k0 + kl) = hv;
    }
}

// Pass 2: C[2048,4096] = A' @ B' (B' as B^T [N][K]), scale_b fused epilogue.
// 128x128 tile, BK=64 (32 MFMA per barrier, 64 iters), 4 waves (2x2 of 64x64),
// mfma_f32_16x16x32_f16, global_load_lds width=16.
// XOR swizzle: LDS slot s of row holds global k-chunk kc = s ^ ((row>>1)&7)
// -> fragment ds_read_b128 spreads 64 lanes over all 32 banks (8-cycle min),
//    staging keeps 128B-contiguous-per-row global reads.
__global__ __launch_bounds__(256) void gemm_rs(
    const _Float16* __restrict__ A, const _Float16* __restrict__ Bt,
    const float* __restrict__ scale_b, float* __restrict__ out) {
    __shared__ _Float16 As[128 * BK];   // 16 KB
    __shared__ _Float16 Bs[128 * BK];   // 16 KB

    const int tid  = threadIdx.x;
    const int wid  = tid >> 6;
    const int lane = tid & 63;
    const int quad = lane >> 4;
    const int l16  = lane & 15;
    const int bm   = blockIdx.y * 128;
    const int bn   = blockIdx.x * 128;
    const int wm   = (wid >> 1) * 64;
    const int wn   = (wid & 1) * 64;

    f32x4 acc[4][4] = {};

    const _Float16* Ab = A  + (size_t)bm * H;
    const _Float16* Bb = Bt + (size_t)bn * H;

    // staging: 1024 chunks of 16B per matrix per tile; 4 per thread.
    // chunk c = (t*4+wid)*64 + lane; row = c>>3, slot = c&7,
    // kc = slot ^ ((row>>1)&7); LDS offset = c*16 bytes.
    size_t ga[4];
    char*  laA[4];
    char*  laB[4];
#pragma unroll
    for (int t = 0; t < 4; ++t) {
        int c    = (t * 4 + wid) * 64 + lane;
        int row  = c >> 3;
        int slot = c & 7;
        int kc   = slot ^ ((row >> 1) & 7);
        ga[t]  = (size_t)row * H + kc * 8;
        laA[t] = (char*)As + c * 16;
        laB[t] = (char*)Bs + c * 16;
    }

    // fragment LDS addresses (loop-invariant): for sub-k h (0,1), global
    // k-chunk q = h*4+quad -> LDS slot s = q ^ ((row>>1)&7)
    const _Float16* afp[4][2];
    const _Float16* bfp[4][2];
#pragma unroll
    for (int i = 0; i < 4; ++i) {
        int rowA = wm + i * 16 + l16;
        int rowB = wn + i * 16 + l16;
#pragma unroll
        for (int h = 0; h < 2; ++h) {
            int sA = (h * 4 + quad) ^ ((rowA >> 1) & 7);
            int sB = (h * 4 + quad) ^ ((rowB >> 1) & 7);
            afp[i][h] = &As[rowA * BK + sA * 8];
            bfp[i][h] = &Bs[rowB * BK + sB * 8];
        }
    }

    for (int k0 = 0; k0 < H; k0 += BK) {
#pragma unroll
        for (int t = 0; t < 4; ++t) {
            async_copy16(Ab + ga[t] + k0, laA[t]);
            async_copy16(Bb + ga[t] + k0, laB[t]);
        }
        __syncthreads();

        f16x8 af[4][2], bf[4][2];
#pragma unroll
        for (int i = 0; i < 4; ++i) {
            af[i][0] = *(const f16x8*)afp[i][0];
            af[i][1] = *(const f16x8*)afp[i][1];
            bf[i][0] = *(const f16x8*)bfp[i][0];
            bf[i][1] = *(const f16x8*)bfp[i][1];
        }
#pragma unroll
        for (int h = 0; h < 2; ++h)
#pragma unroll
            for (int i = 0; i < 4; ++i)
#pragma unroll
                for (int j = 0; j < 4; ++j)
                    acc[i][j] = __builtin_amdgcn_mfma_f32_16x16x32_f16(
                        af[i][h], bf[j][h], acc[i][j], 0, 0, 0);
        __syncthreads();
    }

    // Epilogue: D[row=(lane>>4)*4+r][col=lane&15] per 16x16 tile, fp16-round
#pragma unroll
    for (int i = 0; i < 4; ++i) {
#pragma unroll
        for (int j = 0; j < 4; ++j) {
            int col = bn + wn + j * 16 + l16;
            float sb = scale_b[col];
#pragma unroll
            for (int r = 0; r < 4; ++r) {
                int row = bm + wm + i * 16 + quad * 4 + r;
                float v = acc[i][j][r] * sb;
                out[(size_t)row * H + col] = (float)(_Float16)v;
            }
        }
    }
}

extern "C" void kernel_launch(void* const* d_in, const int* in_sizes, int n_in,
                              void* d_out, int out_size, void* d_ws, size_t ws_size,
                              hipStream_t stream) {
    const float* input   = (const float*)d_in[0];   // [16384, 4096] fp32
    const float* weight  = (const float*)d_in[1];   // [4096, 4096] fp32
    const float* scale_b = (const float*)d_in[2];   // [1, 4096] fp32
    float* out = (float*)d_out;                     // [2048, 4096] (fp16 values)

    _Float16* aq = (_Float16*)d_ws;                 // 16 MB
    _Float16* bt = aq + (size_t)MOUT * H;           // 32 MB

    reduce_quant_a<<<(MOUT * H / 4) / 256, 256, 0, stream>>>(input, aq);
    quant_transpose_b<<<dim3(H / 64, H / 64), 256, 0, stream>>>(weight, bt);
    gemm_rs<<<dim3(H / 128, MOUT / 128), 256, 0, stream>>>(aq, bt, scale_b, out);
}